// Round 1
// baseline (36.366 us; speedup 1.0000x reference)
//
#include <hip/hip_runtime.h>
#include <math.h>

#define DIM_   128
#define NAT_   16      // atoms per molecule
#define NTOT_  1024    // total atoms
#define BMOL_  64      // molecules
#define OFFB_  1008.0f // NTOT_ - NAT_ copies of E_bond[0] in each axis-1 norm
#define EPSF_  1e-12f

// K1: mps0[a] = E_fp[fingerprints[a]];  contri[a] = relu(mps0[a] @ W_fp + b_fp)
__global__ void k_embed_contri(const int* __restrict__ fp,
                               const float* __restrict__ E_fp,
                               const float* __restrict__ W_fp,
                               const float* __restrict__ b_fp,
                               float* __restrict__ mps0,
                               float* __restrict__ contri) {
    const int a = blockIdx.x, c = threadIdx.x;
    __shared__ float sm[DIM_];
    const int fid = fp[a];
    const float v = E_fp[fid * DIM_ + c];
    mps0[a * DIM_ + c] = v;
    sm[c] = v;
    __syncthreads();
    float acc = b_fp[c];
    #pragma unroll 8
    for (int k = 0; k < DIM_; ++k) acc += sm[k] * W_fp[k * DIM_ + c];
    contri[a * DIM_ + c] = fmaxf(acc, 0.0f);
}

// K2: mps1[a] = mps0[a] + sum_{j in mol(a)} adj[a, base+j] * contri[base+j]; then row-L2-normalize
__global__ void k_msg_norm(const float* __restrict__ adj,
                           const float* __restrict__ mps0,
                           const float* __restrict__ contri,
                           float* __restrict__ mpsn) {
    const int a = blockIdx.x, c = threadIdx.x;
    const int base = (a >> 4) << 4;
    float acc = mps0[a * DIM_ + c];
    #pragma unroll
    for (int j = 0; j < NAT_; ++j) {
        const float w = adj[a * NTOT_ + base + j];       // wave-uniform -> scalar load
        acc += w * contri[(base + j) * DIM_ + c];
    }
    __shared__ float red[DIM_];
    red[c] = acc * acc;
    __syncthreads();
    for (int s = DIM_ / 2; s > 0; s >>= 1) {
        if (c < s) red[c] += red[c + s];
        __syncthreads();
    }
    const float nrm = fmaxf(sqrtf(red[0]), EPSF_);
    mpsn[a * DIM_ + c] = acc / nrm;
}

// K3: nsq[a,c] = sum_{j in mol} E_bond[idx[a, base+j], c]^2 + 1008*E_bond[0,c]^2
//     msc[a,c] = mpsn[a,c] / max(sqrt(nsq), eps)
__global__ void k_msc(const int* __restrict__ bidx,
                      const float* __restrict__ E_bond,
                      const float* __restrict__ mpsn,
                      float* __restrict__ msc) {
    const int a = blockIdx.x, c = threadIdx.x;
    const int base = (a >> 4) << 4;
    const float e0 = E_bond[c];
    float acc = OFFB_ * e0 * e0;
    #pragma unroll
    for (int j = 0; j < NAT_; ++j) {
        const int id = bidx[a * NTOT_ + base + j];       // wave-uniform
        const float e = E_bond[id * DIM_ + c];
        acc += e * e;
    }
    const float nrm = fmaxf(sqrtf(acc), EPSF_);
    msc[a * DIM_ + c] = mpsn[a * DIM_ + c] / nrm;
}

// K4: per-molecule column sums of msc
__global__ void k_sb(const float* __restrict__ msc, float* __restrict__ Sb) {
    const int m = blockIdx.x, c = threadIdx.x;
    float acc = 0.f;
    #pragma unroll
    for (int j = 0; j < NAT_; ++j) acc += msc[(m * NAT_ + j) * DIM_ + c];
    Sb[m * DIM_ + c] = acc;
}

// K4b: global column sum
__global__ void k_s(const float* __restrict__ Sb, float* __restrict__ S) {
    const int c = threadIdx.x;
    float acc = 0.f;
    for (int m = 0; m < BMOL_; ++m) acc += Sb[m * DIM_ + c];
    S[c] = acc;
}

// K5: tmpT[b,c] = sum_{j in mol(b)} msc[base+j,c]*E_bond[idx[base+j,b],c]
//                 + E_bond[0,c]*(S[c]-Sb[mol(b),c])
__global__ void k_tmp(const int* __restrict__ bidx,
                      const float* __restrict__ E_bond,
                      const float* __restrict__ msc,
                      const float* __restrict__ Sb,
                      const float* __restrict__ S,
                      float* __restrict__ tmpT) {
    const int b = blockIdx.x, c = threadIdx.x;
    const int mol = b >> 4, base = mol << 4;
    float acc = 0.f;
    #pragma unroll
    for (int j = 0; j < NAT_; ++j) {
        const int id = bidx[(base + j) * NTOT_ + b];     // wave-uniform
        acc += msc[(base + j) * DIM_ + c] * E_bond[id * DIM_ + c];
    }
    acc += E_bond[c] * (S[c] - Sb[mol * DIM_ + c]);
    tmpT[b * DIM_ + c] = acc;
}

// K6: tn[m,d] = sum_n tmpT[m*16+n,d]*mpsn[m*16+n,d]; then 2-layer MLP + final dot
__global__ void k_out(const float* __restrict__ tmpT,
                      const float* __restrict__ mpsn,
                      const float* __restrict__ W0, const float* __restrict__ b0,
                      const float* __restrict__ W1, const float* __restrict__ b1,
                      const float* __restrict__ Wp, const float* __restrict__ bp,
                      float* __restrict__ out) {
    const int m = blockIdx.x, t = threadIdx.x;
    __shared__ float sm[DIM_];
    __shared__ float red[DIM_];
    float tn = 0.f;
    #pragma unroll
    for (int n = 0; n < NAT_; ++n) {
        const int a = m * NAT_ + n;
        tn += tmpT[a * DIM_ + t] * mpsn[a * DIM_ + t];
    }
    sm[t] = tn;
    __syncthreads();
    float x0 = b0[t];
    #pragma unroll 8
    for (int d = 0; d < DIM_; ++d) x0 += sm[d] * W0[d * DIM_ + t];
    x0 = fmaxf(x0, 0.f);
    __syncthreads();
    sm[t] = x0;
    __syncthreads();
    float x1 = b1[t];
    #pragma unroll 8
    for (int d = 0; d < DIM_; ++d) x1 += sm[d] * W1[d * DIM_ + t];
    x1 = fmaxf(x1, 0.f);
    red[t] = x1 * Wp[t];
    __syncthreads();
    for (int s = DIM_ / 2; s > 0; s >>= 1) {
        if (t < s) red[t] += red[t + s];
        __syncthreads();
    }
    if (t == 0) out[m] = red[0] + bp[0];
}

extern "C" void kernel_launch(void* const* d_in, const int* in_sizes, int n_in,
                              void* d_out, int out_size, void* d_ws, size_t ws_size,
                              hipStream_t stream) {
    const int*   fingerprints = (const int*)  d_in[0];
    const float* adjacency    = (const float*)d_in[1];
    const int*   bond_index   = (const int*)  d_in[2];
    const float* E_fp         = (const float*)d_in[3];
    const float* E_bond       = (const float*)d_in[4];
    const float* W_fp         = (const float*)d_in[5];
    const float* b_fp         = (const float*)d_in[6];
    const float* W_out0       = (const float*)d_in[7];
    const float* b_out0       = (const float*)d_in[8];
    const float* W_out1       = (const float*)d_in[9];
    const float* b_out1       = (const float*)d_in[10];
    const float* W_prop       = (const float*)d_in[11];
    const float* b_prop       = (const float*)d_in[12];
    float* out = (float*)d_out;

    float* ws = (float*)d_ws;
    const size_t AT = (size_t)NTOT_ * DIM_;   // 131072
    float* mps0   = ws;            // [1024,128]
    float* contri = ws + AT;       // [1024,128]
    float* mpsn   = ws + 2 * AT;   // [1024,128]
    float* msc    = ws + 3 * AT;   // [1024,128]
    float* tmpT   = ws + 4 * AT;   // [1024,128]
    float* Sb     = ws + 5 * AT;   // [64,128]
    float* S      = Sb + (size_t)BMOL_ * DIM_; // [128]

    k_embed_contri<<<NTOT_, DIM_, 0, stream>>>(fingerprints, E_fp, W_fp, b_fp, mps0, contri);
    k_msg_norm   <<<NTOT_, DIM_, 0, stream>>>(adjacency, mps0, contri, mpsn);
    k_msc        <<<NTOT_, DIM_, 0, stream>>>(bond_index, E_bond, mpsn, msc);
    k_sb         <<<BMOL_, DIM_, 0, stream>>>(msc, Sb);
    k_s          <<<1,     DIM_, 0, stream>>>(Sb, S);
    k_tmp        <<<NTOT_, DIM_, 0, stream>>>(bond_index, E_bond, msc, Sb, S, tmpT);
    k_out        <<<BMOL_, DIM_, 0, stream>>>(tmpT, mpsn, W_out0, b_out0, W_out1, b_out1,
                                              W_prop, b_prop, out);
}

// Round 2
// 28.469 us; speedup vs baseline: 1.2774x; 1.2774x over previous
//
#include <hip/hip_runtime.h>
#include <math.h>

#define DIM_   128
#define NAT_   16
#define NTOT_  1024
#define BMOL_  64
#define OFFB_  1008.0f
#define EPSF_  1e-12f

// Kernel A: per-molecule. embed -> contri -> message -> L2norm -> msc -> Sb
// 64 blocks x 256 threads. Thread t: c = t&127 (dim), g = t>>7 (atom group: atoms g*8..g*8+7)
__global__ __launch_bounds__(256) void kA(const int* __restrict__ fp,
                                          const float* __restrict__ Efp,
                                          const float* __restrict__ Wfp,
                                          const float* __restrict__ bfp,
                                          const float* __restrict__ adj,
                                          const int* __restrict__ bidx,
                                          const float* __restrict__ Ebond,
                                          float* __restrict__ mpsn_g,
                                          float* __restrict__ msc_g,
                                          float* __restrict__ Sb_g) {
    const int m = blockIdx.x, base = m * NAT_;
    const int t = threadIdx.x;
    const int c = t & 127;
    const int g = t >> 7;

    __shared__ float mpsS[NAT_][DIM_];
    __shared__ float conS[NAT_][DIM_];
    __shared__ float adjS[NAT_][NAT_];
    __shared__ int   bS[NAT_][NAT_];
    __shared__ float redS[NAT_][2];
    __shared__ float nrmS[NAT_];
    __shared__ float sbS[2][DIM_];

    // load embeddings: 2048 elems, 256 threads -> 8 each
    #pragma unroll
    for (int r = 0; r < 8; ++r) {
        const int idx = t + r * 256;
        const int j = idx >> 7, cc = idx & 127;
        mpsS[j][cc] = Efp[(size_t)fp[base + j] * DIM_ + cc];
    }
    // load 16x16 adjacency block + bond-index block (one elem per thread)
    {
        const int j = t >> 4, i = t & 15;
        adjS[j][i] = adj[(size_t)(base + j) * NTOT_ + base + i];
        bS[j][i]   = bidx[(size_t)(base + j) * NTOT_ + base + i];
    }
    __syncthreads();

    // contri[j][c] = relu(b + sum_k mps[j][k]*W[k][c]) for my 8 atoms
    float acc[8];
    const float bb = bfp[c];
    #pragma unroll
    for (int jj = 0; jj < 8; ++jj) acc[jj] = bb;
    for (int k = 0; k < DIM_; ++k) {
        const float w = Wfp[k * DIM_ + c];
        #pragma unroll
        for (int jj = 0; jj < 8; ++jj) acc[jj] += mpsS[g * 8 + jj][k] * w;
    }
    #pragma unroll
    for (int jj = 0; jj < 8; ++jj) conS[g * 8 + jj][c] = fmaxf(acc[jj], 0.0f);
    __syncthreads();

    // message passing: ms[j][c] = mps[j][c] + sum_i adj[j][i]*contri[i][c]
    float ms[8];
    #pragma unroll
    for (int jj = 0; jj < 8; ++jj) {
        const int j = g * 8 + jj;
        float a = mpsS[j][c];
        #pragma unroll
        for (int i = 0; i < NAT_; ++i) a += adjS[j][i] * conS[i][c];
        ms[jj] = a;
    }
    // rowwise sum of squares: per-wave shuffle reduce, combine two c-halves in LDS
    const int chalf = c >> 6;
    #pragma unroll
    for (int jj = 0; jj < 8; ++jj) {
        const int j = g * 8 + jj;
        float v = ms[jj] * ms[jj];
        for (int o = 32; o > 0; o >>= 1) v += __shfl_xor(v, o, 64);
        if ((t & 63) == 0) redS[j][chalf] = v;
    }
    __syncthreads();
    if (t < NAT_) nrmS[t] = fmaxf(sqrtf(redS[t][0] + redS[t][1]), EPSF_);
    __syncthreads();

    // mpsn; then msc = mpsn / bond-embedding column norm; accumulate Sb
    const float e0 = Ebond[c];
    float sb = 0.0f;
    #pragma unroll
    for (int jj = 0; jj < 8; ++jj) {
        const int j = g * 8 + jj;
        const float mn = ms[jj] / nrmS[j];
        mpsn_g[(size_t)(base + j) * DIM_ + c] = mn;
        float nsq = OFFB_ * e0 * e0;
        #pragma unroll
        for (int i = 0; i < NAT_; ++i) {
            const float e = Ebond[(size_t)bS[j][i] * DIM_ + c];
            nsq += e * e;
        }
        const float v = mn / fmaxf(sqrtf(nsq), EPSF_);
        msc_g[(size_t)(base + j) * DIM_ + c] = v;
        sb += v;
    }
    sbS[g][c] = sb;
    __syncthreads();
    if (g == 0) Sb_g[m * DIM_ + c] = sbS[0][c] + sbS[1][c];
}

// Kernel B: per-molecule. S -> tmp -> tn -> MLP -> out. 64 blocks x 128 threads.
__global__ __launch_bounds__(128) void kB(const int* __restrict__ bidx,
                                          const float* __restrict__ Ebond,
                                          const float* __restrict__ mpsn_g,
                                          const float* __restrict__ msc_g,
                                          const float* __restrict__ Sb_g,
                                          const float* __restrict__ W0, const float* __restrict__ b0,
                                          const float* __restrict__ W1, const float* __restrict__ b1,
                                          const float* __restrict__ Wp, const float* __restrict__ bp,
                                          float* __restrict__ out) {
    const int m = blockIdx.x, base = m * NAT_, c = threadIdx.x;
    __shared__ float mscS[NAT_][DIM_];
    __shared__ float mpsnS[NAT_][DIM_];
    __shared__ int   bS[NAT_][NAT_];
    __shared__ float tnS[DIM_];
    __shared__ float r2[2];

    #pragma unroll
    for (int j = 0; j < NAT_; ++j) {
        mscS[j][c]  = msc_g[(size_t)(base + j) * DIM_ + c];
        mpsnS[j][c] = mpsn_g[(size_t)(base + j) * DIM_ + c];
    }
    #pragma unroll
    for (int r = 0; r < 2; ++r) {
        const int idx = c + r * 128;              // 0..255
        const int j = idx >> 4, i = idx & 15;
        bS[j][i] = bidx[(size_t)(base + j) * NTOT_ + base + i];
    }
    // S[c] = global column sum of msc (from per-molecule partials)
    float S = 0.0f;
    for (int mm = 0; mm < BMOL_; ++mm) S += Sb_g[mm * DIM_ + c];
    const float corr = Ebond[c] * (S - Sb_g[m * DIM_ + c]);
    __syncthreads();

    // tn[c] = sum_n tmp[n][c]*mpsn[n][c], tmp[n][c] = corr + sum_j msc[j][c]*E_bond[bS[j][n]][c]
    float tn = 0.0f;
    for (int n = 0; n < NAT_; ++n) {
        float tmp = corr;
        #pragma unroll
        for (int j = 0; j < NAT_; ++j)
            tmp += mscS[j][c] * Ebond[(size_t)bS[j][n] * DIM_ + c];
        tn += tmp * mpsnS[n][c];
    }
    tnS[c] = tn;
    __syncthreads();

    float x0 = b0[c];
    for (int d = 0; d < DIM_; ++d) x0 += tnS[d] * W0[d * DIM_ + c];
    x0 = fmaxf(x0, 0.0f);
    __syncthreads();
    tnS[c] = x0;
    __syncthreads();
    float x1 = b1[c];
    for (int d = 0; d < DIM_; ++d) x1 += tnS[d] * W1[d * DIM_ + c];
    x1 = fmaxf(x1, 0.0f);

    float v = x1 * Wp[c];
    for (int o = 32; o > 0; o >>= 1) v += __shfl_xor(v, o, 64);
    if ((c & 63) == 0) r2[c >> 6] = v;
    __syncthreads();
    if (c == 0) out[m] = r2[0] + r2[1] + bp[0];
}

extern "C" void kernel_launch(void* const* d_in, const int* in_sizes, int n_in,
                              void* d_out, int out_size, void* d_ws, size_t ws_size,
                              hipStream_t stream) {
    const int*   fingerprints = (const int*)  d_in[0];
    const float* adjacency    = (const float*)d_in[1];
    const int*   bond_index   = (const int*)  d_in[2];
    const float* E_fp         = (const float*)d_in[3];
    const float* E_bond       = (const float*)d_in[4];
    const float* W_fp         = (const float*)d_in[5];
    const float* b_fp         = (const float*)d_in[6];
    const float* W_out0       = (const float*)d_in[7];
    const float* b_out0       = (const float*)d_in[8];
    const float* W_out1       = (const float*)d_in[9];
    const float* b_out1       = (const float*)d_in[10];
    const float* W_prop       = (const float*)d_in[11];
    const float* b_prop       = (const float*)d_in[12];
    float* out = (float*)d_out;

    float* ws = (float*)d_ws;
    const size_t AT = (size_t)NTOT_ * DIM_;
    float* mpsn = ws;            // [1024,128]
    float* msc  = ws + AT;       // [1024,128]
    float* Sb   = ws + 2 * AT;   // [64,128]

    kA<<<BMOL_, 256, 0, stream>>>(fingerprints, E_fp, W_fp, b_fp, adjacency, bond_index,
                                  E_bond, mpsn, msc, Sb);
    kB<<<BMOL_, DIM_, 0, stream>>>(bond_index, E_bond, mpsn, msc, Sb,
                                   W_out0, b_out0, W_out1, b_out1, W_prop, b_prop, out);
}

// Round 3
// 22.984 us; speedup vs baseline: 1.5822x; 1.2386x over previous
//
#include <hip/hip_runtime.h>
#include <math.h>

#define DIM_   128
#define NAT_   16
#define NTOT_  1024
#define BMOL_  64
#define OFFB_  1008.0f
#define EPSF_  1e-12f

// Kernel A: per-molecule, 512 threads. embed -> contri -> message -> L2norm ->
// single-pass bond gather (row-norm + msc + inblock accum) -> TnIn, Mb, Sb.
// Thread t: c = t&127 (dim), s = t>>7 (slot 0..3, owns atoms s*4..s*4+3)
__global__ __launch_bounds__(512) void kA(const int* __restrict__ fp,
                                          const float* __restrict__ Efp,
                                          const float* __restrict__ Wfp,
                                          const float* __restrict__ bfp,
                                          const float* __restrict__ adj,
                                          const int* __restrict__ bidx,
                                          const float* __restrict__ Ebond,
                                          float* __restrict__ TnIn_g,
                                          float* __restrict__ Mb_g,
                                          float* __restrict__ Sb_g) {
    const int m = blockIdx.x, base = m * NAT_;
    const int t = threadIdx.x;
    const int c = t & 127;
    const int s = t >> 7;

    __shared__ float mpsS[NAT_][DIM_];     // embeddings, later overwritten with mpsn
    __shared__ float conS[NAT_][DIM_];
    __shared__ float adjS[NAT_][NAT_];
    __shared__ int   bSh[NAT_][NAT_];
    __shared__ float redS[NAT_][2];
    __shared__ float nrmS[NAT_];
    __shared__ float red4[4][NAT_][DIM_];  // inblock partials per slot
    __shared__ float sb4[4][DIM_];
    __shared__ float tnp[4][DIM_];

    // load embeddings: 2048 elems / 512 threads = 4 each
    #pragma unroll
    for (int r = 0; r < 4; ++r) {
        const int idx = t + r * 512;
        const int j = idx >> 7, cc = idx & 127;
        mpsS[j][cc] = Efp[(size_t)fp[base + j] * DIM_ + cc];
    }
    if (t < 256) {
        const int j = t >> 4, i = t & 15;
        adjS[j][i] = adj[(size_t)(base + j) * NTOT_ + base + i];
        bSh[j][i]  = bidx[(size_t)(base + j) * NTOT_ + base + i];
    }
    __syncthreads();

    // contri for my 4 atoms
    float acc[4];
    const float bb = bfp[c];
    #pragma unroll
    for (int jj = 0; jj < 4; ++jj) acc[jj] = bb;
    for (int k = 0; k < DIM_; ++k) {
        const float w = Wfp[k * DIM_ + c];
        #pragma unroll
        for (int jj = 0; jj < 4; ++jj) acc[jj] += mpsS[s * 4 + jj][k] * w;
    }
    #pragma unroll
    for (int jj = 0; jj < 4; ++jj) conS[s * 4 + jj][c] = fmaxf(acc[jj], 0.0f);
    __syncthreads();

    // message + row L2 norm
    float ms[4];
    #pragma unroll
    for (int jj = 0; jj < 4; ++jj) {
        const int j = s * 4 + jj;
        float a = mpsS[j][c];
        #pragma unroll
        for (int i = 0; i < NAT_; ++i) a += adjS[j][i] * conS[i][c];
        ms[jj] = a;
    }
    const int half = c >> 6;
    #pragma unroll
    for (int jj = 0; jj < 4; ++jj) {
        const int j = s * 4 + jj;
        float v = ms[jj] * ms[jj];
        for (int o = 32; o > 0; o >>= 1) v += __shfl_xor(v, o, 64);
        if ((t & 63) == 0) redS[j][half] = v;
    }
    __syncthreads();
    if (t < NAT_) nrmS[t] = fmaxf(sqrtf(redS[t][0] + redS[t][1]), EPSF_);
    __syncthreads();

    // mpsn for my atoms (store into mpsS)
    float mn[4];
    #pragma unroll
    for (int jj = 0; jj < 4; ++jj) {
        const int j = s * 4 + jj;
        mn[jj] = ms[jj] / nrmS[j];
        mpsS[j][c] = mn[jj];
    }

    // single-pass bond gather: per j, 16 row values -> nsq -> msc_j -> inblock accum
    const float e0 = Ebond[c];
    const float e0sq = OFFB_ * e0 * e0;
    float accIn[NAT_];
    #pragma unroll
    for (int i = 0; i < NAT_; ++i) accIn[i] = 0.0f;
    float sb = 0.0f;
    #pragma unroll
    for (int jj = 0; jj < 4; ++jj) {
        const int j = s * 4 + jj;
        float ev[NAT_];
        #pragma unroll
        for (int i = 0; i < NAT_; ++i)
            ev[i] = Ebond[(size_t)bSh[j][i] * DIM_ + c];
        float nsq = e0sq;
        #pragma unroll
        for (int i = 0; i < NAT_; ++i) nsq += ev[i] * ev[i];
        const float mscj = mn[jj] / fmaxf(sqrtf(nsq), EPSF_);
        sb += mscj;
        #pragma unroll
        for (int i = 0; i < NAT_; ++i) accIn[i] += mscj * ev[i];
    }
    #pragma unroll
    for (int i = 0; i < NAT_; ++i) red4[s][i][c] = accIn[i];
    sb4[s][c] = sb;
    __syncthreads();

    // reduce inblock over slots; partial TnIn per slot (i range = own mpsn writes)
    float tnpart = 0.0f;
    #pragma unroll
    for (int ii = 0; ii < 4; ++ii) {
        const int i = s * 4 + ii;
        const float in_i = red4[0][i][c] + red4[1][i][c] + red4[2][i][c] + red4[3][i][c];
        tnpart += in_i * mpsS[i][c];
    }
    tnp[s][c] = tnpart;
    __syncthreads();

    if (s == 0) {
        const float TnIn = tnp[0][c] + tnp[1][c] + tnp[2][c] + tnp[3][c];
        const float Sb   = sb4[0][c] + sb4[1][c] + sb4[2][c] + sb4[3][c];
        float Mb = 0.0f;
        #pragma unroll
        for (int j = 0; j < NAT_; ++j) Mb += mpsS[j][c];
        TnIn_g[m * DIM_ + c] = TnIn;
        Sb_g[m * DIM_ + c]   = Sb;
        Mb_g[m * DIM_ + c]   = Mb;
    }
}

// Kernel B: per-molecule, 128 threads. S -> tn -> MLP -> out. No gathers.
__global__ __launch_bounds__(128) void kB(const float* __restrict__ Ebond,
                                          const float* __restrict__ TnIn_g,
                                          const float* __restrict__ Mb_g,
                                          const float* __restrict__ Sb_g,
                                          const float* __restrict__ W0, const float* __restrict__ b0,
                                          const float* __restrict__ W1, const float* __restrict__ b1,
                                          const float* __restrict__ Wp, const float* __restrict__ bp,
                                          float* __restrict__ out) {
    const int m = blockIdx.x, c = threadIdx.x;
    __shared__ float tnS[DIM_];
    __shared__ float r2[2];

    float S = 0.0f;
    #pragma unroll 8
    for (int mm = 0; mm < BMOL_; ++mm) S += Sb_g[mm * DIM_ + c];
    const float tn = TnIn_g[m * DIM_ + c]
                   + Ebond[c] * (S - Sb_g[m * DIM_ + c]) * Mb_g[m * DIM_ + c];
    tnS[c] = tn;
    __syncthreads();

    float x0 = b0[c];
    #pragma unroll 8
    for (int d = 0; d < DIM_; ++d) x0 += tnS[d] * W0[d * DIM_ + c];
    x0 = fmaxf(x0, 0.0f);
    __syncthreads();
    tnS[c] = x0;
    __syncthreads();
    float x1 = b1[c];
    #pragma unroll 8
    for (int d = 0; d < DIM_; ++d) x1 += tnS[d] * W1[d * DIM_ + c];
    x1 = fmaxf(x1, 0.0f);

    float v = x1 * Wp[c];
    for (int o = 32; o > 0; o >>= 1) v += __shfl_xor(v, o, 64);
    if ((c & 63) == 0) r2[c >> 6] = v;
    __syncthreads();
    if (c == 0) out[m] = r2[0] + r2[1] + bp[0];
}

extern "C" void kernel_launch(void* const* d_in, const int* in_sizes, int n_in,
                              void* d_out, int out_size, void* d_ws, size_t ws_size,
                              hipStream_t stream) {
    const int*   fingerprints = (const int*)  d_in[0];
    const float* adjacency    = (const float*)d_in[1];
    const int*   bond_index   = (const int*)  d_in[2];
    const float* E_fp         = (const float*)d_in[3];
    const float* E_bond       = (const float*)d_in[4];
    const float* W_fp         = (const float*)d_in[5];
    const float* b_fp         = (const float*)d_in[6];
    const float* W_out0       = (const float*)d_in[7];
    const float* b_out0       = (const float*)d_in[8];
    const float* W_out1       = (const float*)d_in[9];
    const float* b_out1       = (const float*)d_in[10];
    const float* W_prop       = (const float*)d_in[11];
    const float* b_prop       = (const float*)d_in[12];
    float* out = (float*)d_out;

    float* ws = (float*)d_ws;
    const size_t MD = (size_t)BMOL_ * DIM_;
    float* TnIn = ws;           // [64,128]
    float* Mb   = ws + MD;      // [64,128]
    float* Sb   = ws + 2 * MD;  // [64,128]

    kA<<<BMOL_, 512, 0, stream>>>(fingerprints, E_fp, W_fp, b_fp, adjacency, bond_index,
                                  E_bond, TnIn, Mb, Sb);
    kB<<<BMOL_, DIM_, 0, stream>>>(E_bond, TnIn, Mb, Sb,
                                   W_out0, b_out0, W_out1, b_out1, W_prop, b_prop, out);
}